// Round 2
// baseline (825.079 us; speedup 1.0000x reference)
//
#include <hip/hip_runtime.h>
#include <hip/hip_cooperative_groups.h>

namespace cg = cooperative_groups;

// SparseMCFModel — output `flow` depends ONLY on demands, edge_row, edge_col.
// w_e = 1/deg(row_e) exactly (softmax over identical logits per segment), so the
// whole GAT/GRU/decoder pipeline is dead code. Flow recurrence with S_1 = 0:
//   S_{k+1}[col_e] += w_e * (relu(d[row_e]) + S_k[row_e]),  k = 1..9
//   flow_e = w_e * (relu(d[row_e]) + S_10[row_e])
// Single cooperative kernel: 11 grid.sync()s replace 23 kernel launches.
// 3-buffer rotation: step k reads S[(k-1)%3], scatters into S[k%3] (zeroed at
// step k-1... actually at step k-2 via the "zero (k+1)%3" slot), zeroes S[(k+1)%3].

#define N_NODES 20000
#define N_EDGES 200000
#define FLOW_ITERS 10
#define NBLK 512
#define NTHR 256
#define NTOT (NBLK * NTHR)          // 131072 threads
#define EPT 2                       // ceil(N_EDGES / NTOT)

__global__ __launch_bounds__(NTHR, 2)
void mcf_fused(const float* __restrict__ demands,
               const int* __restrict__ edge_row,
               const int* __restrict__ edge_col,
               float* __restrict__ out,
               int* __restrict__ deg,     // [N_NODES]
               float* __restrict__ bufs)  // [3 * N_NODES]
{
    cg::grid_group grid = cg::this_grid();
    const int tid = blockIdx.x * blockDim.x + threadIdx.x;

    float* S0 = bufs;
    float* S1 = bufs + N_NODES;
    float* S2 = bufs + 2 * N_NODES;
    float* S[3] = {S0, S1, S2};

    // ---- Phase A: zero deg + all buffers (ws is poisoned 0xAA) ----
    for (int v = tid; v < N_NODES; v += NTOT) {
        deg[v] = 0;
        S0[v] = 0.0f; S1[v] = 0.0f; S2[v] = 0.0f;
    }
    grid.sync();

    // ---- Phase B: degree histogram; cache edge data in registers ----
    int   rowr[EPT], colr[EPT];
    float dposr[EPT], wr[EPT];
    #pragma unroll
    for (int i = 0; i < EPT; ++i) {
        int e = tid + i * NTOT;
        rowr[i] = -1;
        if (e < N_EDGES) {
            int r = edge_row[e];
            rowr[i]  = r;
            colr[i]  = edge_col[e];
            dposr[i] = fmaxf(demands[r], 0.0f);
            atomicAdd(&deg[r], 1);
        }
    }
    grid.sync();

    // w_e = 1/deg[row_e] — same fp32 division as the reference's e/s (e==1, s==deg)
    #pragma unroll
    for (int i = 0; i < EPT; ++i)
        if (rowr[i] >= 0) wr[i] = 1.0f / (float)deg[rowr[i]];

    // ---- 9 scatter steps; one grid sync each ----
    #pragma unroll 1
    for (int k = 1; k <= FLOW_ITERS - 1; ++k) {
        float* Sprev = S[(k - 1) % 3];
        float* Snext = S[k % 3];
        float* Szero = S[(k + 1) % 3];
        #pragma unroll
        for (int i = 0; i < EPT; ++i) {
            if (rowr[i] >= 0) {
                float s = Sprev[rowr[i]];
                atomicAdd(&Snext[colr[i]], wr[i] * (dposr[i] + s));
            }
        }
        // zero the buffer that step k+1 will scatter into (holds dead S_{k-1})
        for (int v = tid; v < N_NODES; v += NTOT) Szero[v] = 0.0f;
        grid.sync();
    }

    // ---- flow = w * q10[row],  q10 = dpos + S_10 ----
    float* Sfin = S[(FLOW_ITERS - 1) % 3];
    #pragma unroll
    for (int i = 0; i < EPT; ++i) {
        int e = tid + i * NTOT;
        if (e < N_EDGES) out[e] = wr[i] * (dposr[i] + Sfin[rowr[i]]);
    }
}

extern "C" void kernel_launch(void* const* d_in, const int* in_sizes, int n_in,
                              void* d_out, int out_size, void* d_ws, size_t ws_size,
                              hipStream_t stream) {
    const float* demands  = (const float*)d_in[1];
    const int*   edge_row = (const int*)d_in[2];
    const int*   edge_col = (const int*)d_in[3];
    float*       out      = (float*)d_out;

    char* ws = (char*)d_ws;
    int*   deg  = (int*)ws;   ws += N_NODES * sizeof(int);
    float* bufs = (float*)ws;

    void* args[] = {(void*)&demands, (void*)&edge_row, (void*)&edge_col,
                    (void*)&out, (void*)&deg, (void*)&bufs};
    hipLaunchCooperativeKernel((const void*)mcf_fused, dim3(NBLK), dim3(NTHR),
                               args, 0, stream);
}

// Round 3
// 700.023 us; speedup vs baseline: 1.1786x; 1.1786x over previous
//
#include <hip/hip_runtime.h>

// SparseMCFModel — output `flow` depends ONLY on demands, edge_row, edge_col.
// w_e = 1/deg(row_e) exactly (softmax over identical logits within each segment),
// so the GAT/GRU/decoder pipeline is dead code. Recurrence with S_1 = 0:
//   S_{k+1}[col_e] += w_e * (relu(d[row_e]) + S_k[row_e]),  k = 1..9
//   flow_e = w_e * (relu(d[row_e]) + S_10[row_e])
//
// Round-2 lesson: cg::grid_group::sync() costs ~70 us on 8-XCD gfx950.
// This version uses a hand-rolled agent-scope barrier. Correctness protocol:
// every mutable cross-step location (deg, S buffers) is accessed ONLY through
// coherent-point ops (__hip_atomic_* AGENT scope / atomicAdd), so no stale
// L1/L2 line can ever be observed regardless of barrier cache maintenance.

#define N_NODES 20000
#define N_EDGES 200000
#define FLOW_ITERS 10
#define NBLK 512
#define NTHR 256
#define NTOT (NBLK * NTHR)          // 131072 threads
#define EPT 2                       // ceil(N_EDGES / NTOT)

__device__ __forceinline__ float ld_coh(const float* p) {
    return __hip_atomic_load(p, __ATOMIC_RELAXED, __HIP_MEMORY_SCOPE_AGENT);
}
__device__ __forceinline__ int ld_coh_i(const int* p) {
    return __hip_atomic_load(p, __ATOMIC_RELAXED, __HIP_MEMORY_SCOPE_AGENT);
}
__device__ __forceinline__ void st_coh(float* p, float v) {
    __hip_atomic_store(p, v, __ATOMIC_RELAXED, __HIP_MEMORY_SCOPE_AGENT);
}

// Monotone-counter barrier. target = NBLK * (barrier ordinal).
// Release on arrive: drains this block's outstanding global writes/atomics to
// the coherent point before signaling. Acquire on the spin exit: orders the
// post-barrier accesses; cheap because hot data is in registers or accessed
// via coherent-point ops anyway.
__device__ __forceinline__ void gbar(int* cnt, int target) {
    __syncthreads();
    if (threadIdx.x == 0) {
        __hip_atomic_fetch_add(cnt, 1, __ATOMIC_RELEASE, __HIP_MEMORY_SCOPE_AGENT);
        while (__hip_atomic_load(cnt, __ATOMIC_ACQUIRE, __HIP_MEMORY_SCOPE_AGENT) < target) {
            __builtin_amdgcn_s_sleep(2);
        }
    }
    __syncthreads();
}

__global__ __launch_bounds__(NTHR, 2)
void mcf_fused(const float* __restrict__ demands,
               const int* __restrict__ edge_row,
               const int* __restrict__ edge_col,
               float* __restrict__ out,
               int* __restrict__ deg,     // [N_NODES]
               float* __restrict__ bufs,  // [3 * N_NODES]
               int* __restrict__ barcnt)  // [1], memset to 0 before launch
{
    const int tid = blockIdx.x * blockDim.x + threadIdx.x;
    int bar = 0;

    float* S[3] = {bufs, bufs + N_NODES, bufs + 2 * N_NODES};

    // ---- Phase A: zero deg + all S buffers (ws poisoned 0xAA) ----
    for (int v = tid; v < N_NODES; v += NTOT) {
        __hip_atomic_store(&deg[v], 0, __ATOMIC_RELAXED, __HIP_MEMORY_SCOPE_AGENT);
        st_coh(&S[0][v], 0.0f);
        st_coh(&S[1][v], 0.0f);
        st_coh(&S[2][v], 0.0f);
    }
    gbar(barcnt, NBLK * (++bar));

    // ---- Phase B: degree histogram; cache edge data in registers ----
    int   rowr[EPT], colr[EPT];
    float dposr[EPT], wr[EPT];
    #pragma unroll
    for (int i = 0; i < EPT; ++i) {
        int e = tid + i * NTOT;
        rowr[i] = -1;
        if (e < N_EDGES) {
            int r = edge_row[e];
            rowr[i]  = r;
            colr[i]  = edge_col[e];
            dposr[i] = fmaxf(demands[r], 0.0f);
            atomicAdd(&deg[r], 1);          // fire-and-forget, coherent point
        }
    }
    gbar(barcnt, NBLK * (++bar));

    // w_e = 1/deg[row_e] — same fp32 division as reference (e=1, s=deg)
    #pragma unroll
    for (int i = 0; i < EPT; ++i)
        if (rowr[i] >= 0) wr[i] = 1.0f / (float)ld_coh_i(&deg[rowr[i]]);

    // ---- 9 scatter steps, one barrier each ----
    #pragma unroll 1
    for (int k = 1; k <= FLOW_ITERS - 1; ++k) {
        float* Sprev = S[(k - 1) % 3];
        float* Snext = S[k % 3];
        float* Szero = S[(k + 1) % 3];
        #pragma unroll
        for (int i = 0; i < EPT; ++i) {
            if (rowr[i] >= 0) {
                float s = ld_coh(&Sprev[rowr[i]]);
                atomicAdd(&Snext[colr[i]], wr[i] * (dposr[i] + s));  // fire-and-forget
            }
        }
        // zero the buffer step k+1 scatters into (holds dead S_{k-1})
        for (int v = tid; v < N_NODES; v += NTOT) st_coh(&Szero[v], 0.0f);
        gbar(barcnt, NBLK * (++bar));
    }

    // ---- flow = w * (dpos + S_10[row]) ----
    float* Sfin = S[(FLOW_ITERS - 1) % 3];
    #pragma unroll
    for (int i = 0; i < EPT; ++i) {
        int e = tid + i * NTOT;
        if (e < N_EDGES) out[e] = wr[i] * (dposr[i] + ld_coh(&Sfin[rowr[i]]));
    }
}

extern "C" void kernel_launch(void* const* d_in, const int* in_sizes, int n_in,
                              void* d_out, int out_size, void* d_ws, size_t ws_size,
                              hipStream_t stream) {
    const float* demands  = (const float*)d_in[1];
    const int*   edge_row = (const int*)d_in[2];
    const int*   edge_col = (const int*)d_in[3];
    float*       out      = (float*)d_out;

    char* ws = (char*)d_ws;
    int*   deg    = (int*)ws;   ws += N_NODES * sizeof(int);
    float* bufs   = (float*)ws; ws += 3 * N_NODES * sizeof(float);
    int*   barcnt = (int*)ws;

    hipMemsetAsync(barcnt, 0, sizeof(int), stream);

    void* args[] = {(void*)&demands, (void*)&edge_row, (void*)&edge_col,
                    (void*)&out, (void*)&deg, (void*)&bufs, (void*)&barcnt};
    hipLaunchCooperativeKernel((const void*)mcf_fused, dim3(NBLK), dim3(NTHR),
                               args, 0, stream);
}

// Round 4
// 328.806 us; speedup vs baseline: 2.5093x; 2.1290x over previous
//
#include <hip/hip_runtime.h>

// SparseMCFModel — output `flow` depends ONLY on demands, edge_row, edge_col.
// w_e = 1/deg(row_e) exactly (softmax over identical logits within each segment),
// so the GAT/GRU/decoder pipeline is dead code. Recurrence with S_1 = 0:
//   S_{k+1}[col_e] += w_e * (relu(d[row_e]) + S_k[row_e]),  k = 1..9
//   flow_e = w_e * (relu(d[row_e]) + S_10[row_e])
//
// Round-2/3 lesson: BOTH cg::grid_sync and a custom barrier that POLLS with
// ACQUIRE cost ~55 us/iter — every agent-scope acquire poll emits L1/L2
// cache-maintenance (buffer_inv), and hundreds of spinners trash all XCD L2s
// continuously. Fix: poll RELAXED (no cache ops), then exactly ONE acquire
// load per block after spin exit. Release(fetch_add) -> relaxed-observe ->
// acquire(load of release-sequence value) gives a proper synchronizes-with
// chain, so bulk data (S buffers, deg reads) can use PLAIN cached loads and
// stores: gathers hit the XCD-L2-resident 80 KB buffer instead of the
// coherent point. atomicAdd (true RMW) kept for histogram + scatter.

#define N_NODES 20000
#define N_EDGES 200000
#define FLOW_ITERS 10
#define NBLK 128
#define NTHR 512
#define NTOT (NBLK * NTHR)          // 65536 threads
#define EPT 4                       // ceil(N_EDGES / NTOT)

// Monotone-counter barrier, target = NBLK * ordinal. Relaxed polls with
// backoff; single acquire at exit establishes visibility of all pre-barrier
// writes (release fetch_add writes back L2; acquire invalidates L1/L2 once).
__device__ __forceinline__ void gbar(int* cnt, int target) {
    __syncthreads();   // compiler drains vmcnt before s_barrier -> block's
                       // stores are in (write-through) L1/L2 before release
    if (threadIdx.x == 0) {
        __hip_atomic_fetch_add(cnt, 1, __ATOMIC_RELEASE, __HIP_MEMORY_SCOPE_AGENT);
        while (__hip_atomic_load(cnt, __ATOMIC_RELAXED, __HIP_MEMORY_SCOPE_AGENT) < target)
            __builtin_amdgcn_s_sleep(8);
        (void)__hip_atomic_load(cnt, __ATOMIC_ACQUIRE, __HIP_MEMORY_SCOPE_AGENT);
    }
    __syncthreads();
}

__global__ __launch_bounds__(NTHR)
void mcf_fused(const float* __restrict__ demands,
               const int* __restrict__ edge_row,
               const int* __restrict__ edge_col,
               float* __restrict__ out,
               int* __restrict__ deg,     // [N_NODES]
               float* __restrict__ bufs,  // [3 * N_NODES]
               int* __restrict__ barcnt)  // [1], memset to 0 before launch
{
    const int tid = blockIdx.x * blockDim.x + threadIdx.x;
    int bar = 0;

    float* S[3] = {bufs, bufs + N_NODES, bufs + 2 * N_NODES};

    // ---- Phase A: zero deg + all S buffers (plain stores; barrier releases) ----
    for (int v = tid; v < N_NODES; v += NTOT) {
        deg[v] = 0;
        S[0][v] = 0.0f; S[1][v] = 0.0f; S[2][v] = 0.0f;
    }
    gbar(barcnt, NBLK * (++bar));

    // ---- Phase B: degree histogram; cache edge data in registers ----
    int   rowr[EPT], colr[EPT];
    float dposr[EPT], wr[EPT];
    #pragma unroll
    for (int i = 0; i < EPT; ++i) {
        int e = tid + i * NTOT;
        rowr[i] = -1;
        if (e < N_EDGES) {
            int r = edge_row[e];
            rowr[i]  = r;
            colr[i]  = edge_col[e];
            dposr[i] = fmaxf(demands[r], 0.0f);
            atomicAdd(&deg[r], 1);          // fire-and-forget RMW
        }
    }
    gbar(barcnt, NBLK * (++bar));

    // w_e = 1/deg[row_e] — plain cached reads (fresh after acquire)
    #pragma unroll
    for (int i = 0; i < EPT; ++i)
        if (rowr[i] >= 0) wr[i] = 1.0f / (float)deg[rowr[i]];

    // ---- 9 scatter steps, one barrier each ----
    #pragma unroll 1
    for (int k = 1; k <= FLOW_ITERS - 1; ++k) {
        float* Sprev = S[(k - 1) % 3];
        float* Snext = S[k % 3];
        float* Szero = S[(k + 1) % 3];
        #pragma unroll
        for (int i = 0; i < EPT; ++i) {
            if (rowr[i] >= 0) {
                float s = Sprev[rowr[i]];   // plain load — L2-resident gather
                atomicAdd(&Snext[colr[i]], wr[i] * (dposr[i] + s));
            }
        }
        // zero the buffer step k+1 scatters into (holds dead S_{k-1});
        // plain stores, pushed to coherent point by this barrier's release.
        for (int v = tid; v < N_NODES; v += NTOT) Szero[v] = 0.0f;
        gbar(barcnt, NBLK * (++bar));
    }

    // ---- flow = w * (dpos + S_10[row]) ----
    float* Sfin = S[(FLOW_ITERS - 1) % 3];
    #pragma unroll
    for (int i = 0; i < EPT; ++i) {
        int e = tid + i * NTOT;
        if (e < N_EDGES) out[e] = wr[i] * (dposr[i] + Sfin[rowr[i]]);
    }
}

extern "C" void kernel_launch(void* const* d_in, const int* in_sizes, int n_in,
                              void* d_out, int out_size, void* d_ws, size_t ws_size,
                              hipStream_t stream) {
    const float* demands  = (const float*)d_in[1];
    const int*   edge_row = (const int*)d_in[2];
    const int*   edge_col = (const int*)d_in[3];
    float*       out      = (float*)d_out;

    char* ws = (char*)d_ws;
    int*   deg    = (int*)ws;   ws += N_NODES * sizeof(int);
    float* bufs   = (float*)ws; ws += 3 * N_NODES * sizeof(float);
    int*   barcnt = (int*)ws;

    hipMemsetAsync(barcnt, 0, sizeof(int), stream);

    void* args[] = {(void*)&demands, (void*)&edge_row, (void*)&edge_col,
                    (void*)&out, (void*)&deg, (void*)&bufs, (void*)&barcnt};
    hipLaunchCooperativeKernel((const void*)mcf_fused, dim3(NBLK), dim3(NTHR),
                               args, 0, stream);
}

// Round 5
// 268.112 us; speedup vs baseline: 3.0774x; 1.2264x over previous
//
#include <hip/hip_runtime.h>

// SparseMCFModel — output `flow` depends ONLY on demands, edge_row, edge_col.
// w_e = 1/deg(row_e) exactly (softmax over identical logits per segment) -> the
// GAT/GRU/decoder pipeline is dead code. With c_e = w_e*relu(d[row_e]):
//   flow_k[e] = c_e + w_e * S_{k-1}[row_e],   S_k[v] = sum_{e: col_e=v} flow_k[e]
//   output = flow_10, needs S_9.
//
// Round-4 lessons: (a) fp32 atomicAdd writes through to memory side (~36 B HBM
// write per atomic; WRITE_SIZE 64 MB == atomic count) and the per-iter 200K
// colliding RMWs cost ~18 us/iter -> switch to CSC GATHER (no atomics in loop).
// (b) ~100 us fixed overhead on the cooperative-launch path -> plain launch
// (128 blocks <= 256 CUs, trivially co-resident) + CAS-init of the barrier
// counter from the 0xAA poison (idempotent: counter never equals poison once
// valid). (c) relaxed-poll barrier; acquire only where plain cached reads of
// freshly-written data follow (build phases). Iteration barriers skip the
// acquire: S is accessed only via agent-scope relaxed atomics (cache-bypassing,
// coherent point), CSC/off data is immutable after the build -> L1 stays hot.

#define N_NODES 20000
#define N_EDGES 200000
#define FLOW_ITERS 10
#define NBLK 128
#define NTHR 512
#define NTOT (NBLK * NTHR)                    // 65536
#define EPT ((N_EDGES + NTOT - 1) / NTOT)     // 4
#define CHUNK ((N_NODES + NBLK - 1) / NBLK)   // 157 nodes per block for the scan
#define CHUNK_P2 256
#define POISON_I ((int)0xAAAAAAAA)

__device__ __forceinline__ float ld_coh(const float* p) {
    return __hip_atomic_load(p, __ATOMIC_RELAXED, __HIP_MEMORY_SCOPE_AGENT);
}
__device__ __forceinline__ void st_coh(float* p, float v) {
    __hip_atomic_store(p, v, __ATOMIC_RELAXED, __HIP_MEMORY_SCOPE_AGENT);
}

// Monotone-counter grid barrier. Release arrive (pushes this block's prior
// plain stores to the coherent point), RELAXED poll (no cache maintenance!),
// optional single acquire at exit (only when plain cached reads of
// barrier-ordered data follow).
__device__ __forceinline__ void gbar(int* cnt, int target, bool acquire) {
    __syncthreads();
    if (threadIdx.x == 0) {
        __hip_atomic_fetch_add(cnt, 1, __ATOMIC_RELEASE, __HIP_MEMORY_SCOPE_AGENT);
        while (__hip_atomic_load(cnt, __ATOMIC_RELAXED, __HIP_MEMORY_SCOPE_AGENT) < target)
            __builtin_amdgcn_s_sleep(8);
        if (acquire)
            (void)__hip_atomic_load(cnt, __ATOMIC_ACQUIRE, __HIP_MEMORY_SCOPE_AGENT);
    }
    __syncthreads();
}

__global__ __launch_bounds__(NTHR)
void mcf_fused(const float* __restrict__ demands,
               const int* __restrict__ edge_row,
               const int* __restrict__ edge_col,
               float* __restrict__ out,
               int* __restrict__ deg,       // [N]  out-degree
               int* __restrict__ indeg,     // [N]  in-degree
               int* __restrict__ off,       // [N+1] CSC offsets
               int* __restrict__ fill,      // [N]  placement cursors
               int* __restrict__ blocksum,  // [NBLK]
               float* __restrict__ S0,      // [N]
               float* __restrict__ S1,      // [N]
               int* __restrict__ csc_row,   // [E]
               float* __restrict__ csc_w,   // [E]
               float* __restrict__ csc_c,   // [E]
               int* __restrict__ barcnt)    // [1], self-initialized from poison
{
    const int tid = blockIdx.x * NTHR + threadIdx.x;
    int bar = 0;

    __shared__ int lds[CHUNK_P2];
    __shared__ int bprefix;

    // ---- self-init barrier counter from 0xAA poison (idempotent CAS) ----
    if (threadIdx.x == 0) atomicCAS(barcnt, POISON_I, 0);

    // ---- Phase A: zero histograms + S0 ----
    for (int v = tid; v < N_NODES; v += NTOT) {
        deg[v] = 0;
        indeg[v] = 0;
        st_coh(&S0[v], 0.0f);
    }
    gbar(barcnt, NBLK * (++bar), false);   // consumers are memory-side atomics

    // ---- Phase B: histograms; cache this thread's edges in registers ----
    int   rowr[EPT], colr[EPT];
    float dposr[EPT], wr[EPT];
    #pragma unroll
    for (int i = 0; i < EPT; ++i) {
        int e = tid + i * NTOT;
        rowr[i] = -1;
        if (e < N_EDGES) {
            int r = edge_row[e], c = edge_col[e];
            rowr[i]  = r;
            colr[i]  = c;
            dposr[i] = fmaxf(demands[r], 0.0f);
            atomicAdd(&deg[r], 1);
            atomicAdd(&indeg[c], 1);
        }
    }
    gbar(barcnt, NBLK * (++bar), true);    // plain reads of deg/indeg follow

    #pragma unroll
    for (int i = 0; i < EPT; ++i)
        if (rowr[i] >= 0) wr[i] = 1.0f / (float)deg[rowr[i]];

    // ---- Phase C: per-block inclusive scan of indeg chunk (LDS) ----
    const int base = blockIdx.x * CHUNK;
    for (int t = threadIdx.x; t < CHUNK_P2; t += NTHR) {
        int v = base + t;
        lds[t] = (t < CHUNK && v < N_NODES) ? indeg[v] : 0;
    }
    __syncthreads();
    for (int ofs = 1; ofs < CHUNK_P2; ofs <<= 1) {
        int val = 0;
        if (threadIdx.x < CHUNK_P2) {
            val = lds[threadIdx.x];
            if (threadIdx.x >= ofs) val += lds[threadIdx.x - ofs];
        }
        __syncthreads();
        if (threadIdx.x < CHUNK_P2) lds[threadIdx.x] = val;
        __syncthreads();
    }
    if (threadIdx.x == 0) blocksum[blockIdx.x] = lds[CHUNK_P2 - 1];
    gbar(barcnt, NBLK * (++bar), true);    // plain reads of blocksum follow

    // ---- Phase D: global offsets = block prefix + local exclusive scan ----
    if (threadIdx.x == 0) {
        int p = 0;
        for (int b = 0; b < blockIdx.x; ++b) p += blocksum[b];
        bprefix = p;
    }
    __syncthreads();
    for (int t = threadIdx.x; t < CHUNK; t += NTHR) {
        int v = base + t;
        if (v < N_NODES) {
            int o = bprefix + (t ? lds[t - 1] : 0);   // exclusive
            off[v]  = o;
            fill[v] = o;
        }
    }
    if (blockIdx.x == NBLK - 1 && threadIdx.x == 0) off[N_NODES] = N_EDGES;
    gbar(barcnt, NBLK * (++bar), true);    // atomics on fill + later reads of off

    // ---- Phase E: CSC placement ----
    #pragma unroll
    for (int i = 0; i < EPT; ++i) {
        if (rowr[i] >= 0) {
            int idx = atomicAdd(&fill[colr[i]], 1);
            csc_row[idx] = rowr[i];
            csc_w[idx]   = wr[i];
            csc_c[idx]   = wr[i] * dposr[i];
        }
    }
    gbar(barcnt, NBLK * (++bar), true);    // plain reads of csc_* follow

    // ---- 9 gather iterations: S_k[v] = sum_j (c_j + w_j * S_{k-1}[row_j]) ----
    #pragma unroll 1
    for (int k = 1; k <= FLOW_ITERS - 1; ++k) {
        const float* Sp = (k & 1) ? S0 : S1;
        float*       Sn = (k & 1) ? S1 : S0;
        for (int v = tid; v < N_NODES; v += NTOT) {
            int j0 = off[v], j1 = off[v + 1];
            float acc = 0.0f;
            for (int j = j0; j < j1; ++j)
                acc += csc_c[j] + csc_w[j] * ld_coh(&Sp[csc_row[j]]);
            st_coh(&Sn[v], acc);
        }
        gbar(barcnt, NBLK * (++bar), false);  // S via coherent ops; csc immutable
    }

    // ---- flow_10[e] = w_e * (dpos_e + S_9[row_e])  (S_9 lives in S1) ----
    #pragma unroll
    for (int i = 0; i < EPT; ++i) {
        int e = tid + i * NTOT;
        if (e < N_EDGES) out[e] = wr[i] * (dposr[i] + ld_coh(&S1[rowr[i]]));
    }
}

extern "C" void kernel_launch(void* const* d_in, const int* in_sizes, int n_in,
                              void* d_out, int out_size, void* d_ws, size_t ws_size,
                              hipStream_t stream) {
    const float* demands  = (const float*)d_in[1];
    const int*   edge_row = (const int*)d_in[2];
    const int*   edge_col = (const int*)d_in[3];
    float*       out      = (float*)d_out;

    char* ws = (char*)d_ws;
    auto take = [&](size_t bytes) {
        void* p = (void*)ws;
        ws += (bytes + 63) & ~size_t(63);   // 64B-align each region
        return p;
    };
    int*   deg      = (int*)  take(N_NODES * 4);
    int*   indeg    = (int*)  take(N_NODES * 4);
    int*   off      = (int*)  take((N_NODES + 1) * 4);
    int*   fill     = (int*)  take(N_NODES * 4);
    int*   blocksum = (int*)  take(NBLK * 4);
    float* S0       = (float*)take(N_NODES * 4);
    float* S1       = (float*)take(N_NODES * 4);
    int*   csc_row  = (int*)  take(N_EDGES * 4);
    float* csc_w    = (float*)take(N_EDGES * 4);
    float* csc_c    = (float*)take(N_EDGES * 4);
    int*   barcnt   = (int*)  take(4);

    mcf_fused<<<NBLK, NTHR, 0, stream>>>(demands, edge_row, edge_col, out,
                                         deg, indeg, off, fill, blocksum,
                                         S0, S1, csc_row, csc_w, csc_c, barcnt);
}

// Round 6
// 198.529 us; speedup vs baseline: 4.1560x; 1.3505x over previous
//
#include <hip/hip_runtime.h>

// SparseMCFModel — output `flow` depends ONLY on demands, edge_row, edge_col.
// w_e = 1/deg(row_e) exactly (softmax over identical logits per segment) -> the
// GAT/GRU/decoder pipeline is dead code. With c_e = w_e*relu(d[row_e]):
//   flow_k[e] = c_e + w_e * S_{k-1}[row_e],   S_k[v] = sum_{e: col_e=v} flow_k[e]
//   output = flow_10 (needs S_9).
//
// Round-5 lesson: removing per-iter atomics barely helped -> per-iter cost is
// (a) the barrier's RELEASE (emits buffer_wbl2 = L2 writeback, ~us-scale) and
// (b) the runtime-bound gather loop's ~10 DEPENDENT ~900cy L3 loads.
// This round: barrier with ZERO cache maintenance (syncthreads already drains
// vmcnt per-wave before s_barrier; all cross-block data uses coherent-point
// ops, so relaxed arrive/poll is sufficient), and per-node edge data cached in
// REGISTERS (cap 24; deg~Poisson(10), P(>24)~3e-5) so each iteration issues 24
// INDEPENDENT L3 loads -> one latency round-trip instead of ten.

#define N_NODES 20000
#define N_EDGES 200000
#define FLOW_ITERS 10
#define NBLK 128
#define NTHR 512
#define NTOT (NBLK * NTHR)                    // 65536
#define EPT ((N_EDGES + NTOT - 1) / NTOT)     // 4 edges/thread (build phases)
#define CHUNK ((N_NODES + NBLK - 1) / NBLK)   // 157 nodes/block (scan)
#define CHUNK_P2 256
#define CAP 24                                // register-cached edges per node
#define POISON_I ((int)0xAAAAAAAA)

__device__ __forceinline__ float ld_coh(const float* p) {
    return __hip_atomic_load(p, __ATOMIC_RELAXED, __HIP_MEMORY_SCOPE_AGENT);
}
__device__ __forceinline__ int ld_coh_i(const int* p) {
    return __hip_atomic_load(p, __ATOMIC_RELAXED, __HIP_MEMORY_SCOPE_AGENT);
}
__device__ __forceinline__ void st_coh(float* p, float v) {
    __hip_atomic_store(p, v, __ATOMIC_RELAXED, __HIP_MEMORY_SCOPE_AGENT);
}
__device__ __forceinline__ void st_coh_i(int* p, int v) {
    __hip_atomic_store(p, v, __ATOMIC_RELAXED, __HIP_MEMORY_SCOPE_AGENT);
}

// Monotone-counter barrier with NO acquire/release cache ops. Sound because:
// __syncthreads() makes every wave drain vmcnt(0) before s_barrier (compiler-
// guaranteed), so all the block's coherent-point writes are globally visible
// before thread0's relaxed arrive; all cross-block reads after the barrier use
// coherent-point ops (or touch lines never cached stale — see CSC note).
__device__ __forceinline__ void gbar(int* cnt, int target) {
    __syncthreads();
    if (threadIdx.x == 0) {
        __hip_atomic_fetch_add(cnt, 1, __ATOMIC_RELAXED, __HIP_MEMORY_SCOPE_AGENT);
        while (__hip_atomic_load(cnt, __ATOMIC_RELAXED, __HIP_MEMORY_SCOPE_AGENT) < target)
            __builtin_amdgcn_s_sleep(4);
    }
    __syncthreads();
}

__global__ __launch_bounds__(NTHR)
void mcf_fused(const float* __restrict__ demands,
               const int* __restrict__ edge_row,
               const int* __restrict__ edge_col,
               float* __restrict__ out,
               int* __restrict__ deg,       // [N]  out-degree
               int* __restrict__ indeg,     // [N]  in-degree
               int* __restrict__ off,       // [N+1] CSC offsets
               int* __restrict__ fill,      // [N]  placement cursors
               int* __restrict__ blocksum,  // [NBLK]
               float* __restrict__ S0,      // [N]
               float* __restrict__ S1,      // [N]
               int* __restrict__ csc_row,   // [E]
               float* __restrict__ csc_w,   // [E]
               float* __restrict__ csc_c,   // [E]
               int* __restrict__ barcnt)    // [1], CAS-initialized from poison
{
    const int tid = blockIdx.x * NTHR + threadIdx.x;
    int bar = 0;

    __shared__ int lds[CHUNK_P2];   // per-block node-chunk scan
    __shared__ int ldsb[NBLK];      // block-sum scan

    // self-init barrier counter from 0xAA poison (idempotent, race-safe)
    if (threadIdx.x == 0) atomicCAS(barcnt, POISON_I, 0);

    // ---- Phase A: zero histograms + S0 ----
    for (int v = tid; v < N_NODES; v += NTOT) {
        st_coh_i(&deg[v], 0);
        st_coh_i(&indeg[v], 0);
        st_coh(&S0[v], 0.0f);
    }
    gbar(barcnt, NBLK * (++bar));

    // ---- Phase B: histograms; cache this thread's edges in registers ----
    int   rowr[EPT], colr[EPT];
    float dposr[EPT], wr[EPT];
    #pragma unroll
    for (int i = 0; i < EPT; ++i) {
        int e = tid + i * NTOT;
        rowr[i] = -1;
        if (e < N_EDGES) {
            int r = edge_row[e], c = edge_col[e];
            rowr[i]  = r;
            colr[i]  = c;
            dposr[i] = fmaxf(demands[r], 0.0f);
            __hip_atomic_fetch_add(&deg[r], 1, __ATOMIC_RELAXED, __HIP_MEMORY_SCOPE_AGENT);
            __hip_atomic_fetch_add(&indeg[c], 1, __ATOMIC_RELAXED, __HIP_MEMORY_SCOPE_AGENT);
        }
    }
    gbar(barcnt, NBLK * (++bar));

    #pragma unroll
    for (int i = 0; i < EPT; ++i)
        if (rowr[i] >= 0) wr[i] = 1.0f / (float)ld_coh_i(&deg[rowr[i]]);

    // ---- Phase C: per-block inclusive scan of this block's indeg chunk ----
    const int base = blockIdx.x * CHUNK;
    for (int t = threadIdx.x; t < CHUNK_P2; t += NTHR) {
        int v = base + t;
        lds[t] = (t < CHUNK && v < N_NODES) ? ld_coh_i(&indeg[v]) : 0;
    }
    __syncthreads();
    for (int ofs = 1; ofs < CHUNK_P2; ofs <<= 1) {
        int val = 0;
        if (threadIdx.x < CHUNK_P2) {
            val = lds[threadIdx.x];
            if (threadIdx.x >= ofs) val += lds[threadIdx.x - ofs];
        }
        __syncthreads();
        if (threadIdx.x < CHUNK_P2) lds[threadIdx.x] = val;
        __syncthreads();
    }
    if (threadIdx.x == 0) st_coh_i(&blocksum[blockIdx.x], lds[CHUNK_P2 - 1]);
    gbar(barcnt, NBLK * (++bar));

    // ---- Phase D: block prefix (parallel 128-scan) + global offsets ----
    if (threadIdx.x < NBLK) ldsb[threadIdx.x] = ld_coh_i(&blocksum[threadIdx.x]);
    __syncthreads();
    for (int ofs = 1; ofs < NBLK; ofs <<= 1) {
        int val = 0;
        if (threadIdx.x < NBLK) {
            val = ldsb[threadIdx.x];
            if (threadIdx.x >= ofs) val += ldsb[threadIdx.x - ofs];
        }
        __syncthreads();
        if (threadIdx.x < NBLK) ldsb[threadIdx.x] = val;
        __syncthreads();
    }
    const int bprefix = (blockIdx.x > 0) ? ldsb[blockIdx.x - 1] : 0;
    for (int t = threadIdx.x; t < CHUNK; t += NTHR) {
        int v = base + t;
        if (v < N_NODES) {
            int o = bprefix + (t ? lds[t - 1] : 0);   // exclusive
            st_coh_i(&off[v], o);
            st_coh_i(&fill[v], o);
        }
    }
    if (blockIdx.x == NBLK - 1 && threadIdx.x == 0) st_coh_i(&off[N_NODES], N_EDGES);
    gbar(barcnt, NBLK * (++bar));

    // ---- Phase E: CSC placement (st_coh writes -> safe for later plain reads:
    // these lines were never cached by anyone, and st_coh bypasses L1/L2, so a
    // post-barrier plain read must miss to L3 and see fresh data) ----
    #pragma unroll
    for (int i = 0; i < EPT; ++i) {
        if (rowr[i] >= 0) {
            int idx = __hip_atomic_fetch_add(&fill[colr[i]], 1,
                                             __ATOMIC_RELAXED, __HIP_MEMORY_SCOPE_AGENT);
            st_coh_i(&csc_row[idx], rowr[i]);
            st_coh(&csc_w[idx], wr[i]);
            st_coh(&csc_c[idx], wr[i] * dposr[i]);
        }
    }
    gbar(barcnt, NBLK * (++bar));

    // ---- Register-cache this thread's node's edges (plain, L1-hot after) ----
    const int v = tid;
    const bool active = (v < N_NODES);
    int j0 = 0, j1 = 0;
    int   er[CAP];
    float ew[CAP], ec[CAP];
    if (active) {
        j0 = off[v]; j1 = off[v + 1];
        #pragma unroll
        for (int k = 0; k < CAP; ++k) {
            int  jj = j0 + k;
            bool in = (jj < j1);
            int  je = in ? jj : 0;          // safe dummy slot
            er[k] = csc_row[je];
            ew[k] = in ? csc_w[je] : 0.0f;
            ec[k] = in ? csc_c[je] : 0.0f;
        }
    }

    // ---- 9 gather iterations: 24 INDEPENDENT coherent loads, one round-trip ----
    #pragma unroll 1
    for (int k = 1; k <= FLOW_ITERS - 1; ++k) {
        const float* Sp = (k & 1) ? S0 : S1;
        float*       Sn = (k & 1) ? S1 : S0;
        if (active) {
            float sk[CAP];
            #pragma unroll
            for (int t = 0; t < CAP; ++t) sk[t] = ld_coh(&Sp[er[t]]);
            float acc = 0.0f;
            #pragma unroll
            for (int t = 0; t < CAP; ++t) acc += ec[t] + ew[t] * sk[t];
            for (int j = j0 + CAP; j < j1; ++j)          // ~never taken
                acc += csc_c[j] + csc_w[j] * ld_coh(&Sp[csc_row[j]]);
            st_coh(&Sn[v], acc);
        }
        gbar(barcnt, NBLK * (++bar));
    }

    // ---- flow_10[e] = w_e * (dpos_e + S_9[row_e])  (S_9 lives in S1) ----
    #pragma unroll
    for (int i = 0; i < EPT; ++i) {
        int e = tid + i * NTOT;
        if (e < N_EDGES) out[e] = wr[i] * (dposr[i] + ld_coh(&S1[rowr[i]]));
    }
}

extern "C" void kernel_launch(void* const* d_in, const int* in_sizes, int n_in,
                              void* d_out, int out_size, void* d_ws, size_t ws_size,
                              hipStream_t stream) {
    const float* demands  = (const float*)d_in[1];
    const int*   edge_row = (const int*)d_in[2];
    const int*   edge_col = (const int*)d_in[3];
    float*       out      = (float*)d_out;

    char* ws = (char*)d_ws;
    auto take = [&](size_t bytes) {
        void* p = (void*)ws;
        ws += (bytes + 63) & ~size_t(63);
        return p;
    };
    int*   deg      = (int*)  take(N_NODES * 4);
    int*   indeg    = (int*)  take(N_NODES * 4);
    int*   off      = (int*)  take((N_NODES + 1) * 4);
    int*   fill     = (int*)  take(N_NODES * 4);
    int*   blocksum = (int*)  take(NBLK * 4);
    float* S0       = (float*)take(N_NODES * 4);
    float* S1       = (float*)take(N_NODES * 4);
    int*   csc_row  = (int*)  take(N_EDGES * 4);
    float* csc_w    = (float*)take(N_EDGES * 4);
    float* csc_c    = (float*)take(N_EDGES * 4);
    int*   barcnt   = (int*)  take(4);

    mcf_fused<<<NBLK, NTHR, 0, stream>>>(demands, edge_row, edge_col, out,
                                         deg, indeg, off, fill, blocksum,
                                         S0, S1, csc_row, csc_w, csc_c, barcnt);
}

// Round 7
// 170.715 us; speedup vs baseline: 4.8331x; 1.1629x over previous
//
#include <hip/hip_runtime.h>

// SparseMCFModel — output `flow` depends ONLY on demands, edge_row, edge_col.
// w_e = 1/deg(row_e) exactly (softmax over identical logits per segment) -> the
// GAT/GRU/decoder pipeline is dead code. With c_e = w_e*relu(d[row_e]):
//   flow_k[e] = c_e + w_e * S_{k-1}[row_e],   S_k[v] = sum_{e: col_e=v} flow_k[e]
//   output = flow_10 (needs S_9).
//
// Round-6 attribution: (a) WRITE_SIZE == #atomics*64B -> every agent-scope RMW
// write-throughs to HBM; minimize atomic count. (b) gather phase was
// concentrated on 39 of 128 blocks; uncoalesced 64-lane loads serialize ~1
// line/cy at L1 -> ~5 us/iter on the loaded CUs. This round:
//  - balanced ownership: node v owned by block v%128, slot v/128
//  - padded fixed-CAP CSC (CAP=32, k-major SoA) -> no indeg histogram, no
//    prefix scans, 2 fewer barriers, 200K fewer atomics; tiny overflow list
//    (expected empty; deg ~ Poisson(10)) preserves exactness
//  - dummy lanes (k >= deg) read S[0] -> wave-broadcast, ~free
// Barrier: zero-cache-op relaxed monotone counter (round-6, validated).

#define N_NODES 20000
#define N_EDGES 200000
#define FLOW_ITERS 10
#define NBLK 128
#define NTHR 512
#define NTOT (NBLK * NTHR)                 // 65536
#define EPT ((N_EDGES + NTOT - 1) / NTOT)  // 4 edges/thread in build phases
#define CAP 32                             // padded CSC slots per node
#define OFL_MAX 4096
#define POISON_I ((int)0xAAAAAAAA)

__device__ __forceinline__ float ld_coh(const float* p) {
    return __hip_atomic_load(p, __ATOMIC_RELAXED, __HIP_MEMORY_SCOPE_AGENT);
}
__device__ __forceinline__ int ld_coh_i(const int* p) {
    return __hip_atomic_load(p, __ATOMIC_RELAXED, __HIP_MEMORY_SCOPE_AGENT);
}
__device__ __forceinline__ void st_coh(float* p, float v) {
    __hip_atomic_store(p, v, __ATOMIC_RELAXED, __HIP_MEMORY_SCOPE_AGENT);
}
__device__ __forceinline__ void st_coh_i(int* p, int v) {
    __hip_atomic_store(p, v, __ATOMIC_RELAXED, __HIP_MEMORY_SCOPE_AGENT);
}

// Monotone-counter barrier, zero cache-maintenance (see round-6 notes):
// __syncthreads() drains vmcnt per wave before s_barrier, so all coherent-
// point writes are globally visible before thread0's relaxed arrive; all
// cross-block mutable reads after the barrier use coherent-point ops.
__device__ __forceinline__ void gbar(int* cnt, int target) {
    __syncthreads();
    if (threadIdx.x == 0) {
        __hip_atomic_fetch_add(cnt, 1, __ATOMIC_RELAXED, __HIP_MEMORY_SCOPE_AGENT);
        while (__hip_atomic_load(cnt, __ATOMIC_RELAXED, __HIP_MEMORY_SCOPE_AGENT) < target)
            __builtin_amdgcn_s_sleep(8);
    }
    __syncthreads();
}

__global__ __launch_bounds__(NTHR)
void mcf_fused(const float* __restrict__ demands,
               const int* __restrict__ edge_row,
               const int* __restrict__ edge_col,
               float* __restrict__ out,
               int* __restrict__ deg,       // [N] out-degree
               int* __restrict__ fill,      // [N] CSC slot cursors (== indeg at end)
               float* __restrict__ S0,      // [N]
               float* __restrict__ S1,      // [N]
               int* __restrict__ csc_row,   // [CAP*N], k-major: [k*N + v]
               float* __restrict__ csc_w,   // [CAP*N]
               float* __restrict__ csc_c,   // [CAP*N]
               int* __restrict__ ofl_cnt,   // [1]
               int* __restrict__ ofl_v,     // [OFL_MAX]
               int* __restrict__ ofl_row,   // [OFL_MAX]
               float* __restrict__ ofl_w,   // [OFL_MAX]
               float* __restrict__ ofl_c,   // [OFL_MAX]
               int* __restrict__ barcnt)    // [1], CAS-initialized from poison
{
    const int tid = blockIdx.x * NTHR + threadIdx.x;
    int bar = 0;

    // self-init barrier counter from 0xAA poison (idempotent, race-safe)
    if (threadIdx.x == 0) atomicCAS(barcnt, POISON_I, 0);

    // ---- Phase A: zero deg, fill, S0, ofl_cnt ----
    for (int v = tid; v < N_NODES; v += NTOT) {
        st_coh_i(&deg[v], 0);
        st_coh_i(&fill[v], 0);
        st_coh(&S0[v], 0.0f);
    }
    if (tid == 0) st_coh_i(ofl_cnt, 0);
    gbar(barcnt, NBLK * (++bar));

    // ---- Phase B: out-degree histogram; cache this thread's edges ----
    int   rowr[EPT], colr[EPT];
    float dposr[EPT], wr[EPT];
    #pragma unroll
    for (int i = 0; i < EPT; ++i) {
        int e = tid + i * NTOT;
        rowr[i] = -1;
        if (e < N_EDGES) {
            int r = edge_row[e], c = edge_col[e];
            rowr[i]  = r;
            colr[i]  = c;
            dposr[i] = fmaxf(demands[r], 0.0f);
            __hip_atomic_fetch_add(&deg[r], 1, __ATOMIC_RELAXED, __HIP_MEMORY_SCOPE_AGENT);
        }
    }
    gbar(barcnt, NBLK * (++bar));

    // ---- Phase C: w = 1/deg[row]; padded-CSC placement ----
    #pragma unroll
    for (int i = 0; i < EPT; ++i) {
        if (rowr[i] >= 0) {
            wr[i] = 1.0f / (float)ld_coh_i(&deg[rowr[i]]);
            int c = colr[i];
            int idx = __hip_atomic_fetch_add(&fill[c], 1,
                                             __ATOMIC_RELAXED, __HIP_MEMORY_SCOPE_AGENT);
            float ce = wr[i] * dposr[i];
            if (idx < CAP) {
                st_coh_i(&csc_row[idx * N_NODES + c], rowr[i]);
                st_coh  (&csc_w  [idx * N_NODES + c], wr[i]);
                st_coh  (&csc_c  [idx * N_NODES + c], ce);
            } else {
                int o = __hip_atomic_fetch_add(ofl_cnt, 1,
                                               __ATOMIC_RELAXED, __HIP_MEMORY_SCOPE_AGENT);
                if (o < OFL_MAX) {
                    st_coh_i(&ofl_v[o], c);
                    st_coh_i(&ofl_row[o], rowr[i]);
                    st_coh  (&ofl_w[o], wr[i]);
                    st_coh  (&ofl_c[o], ce);
                }
            }
        }
    }
    gbar(barcnt, NBLK * (++bar));

    // ---- Register-cache owned node's edges (balanced: v = bx + 128*tx) ----
    const int v = blockIdx.x + NBLK * (int)threadIdx.x;
    const bool active = (v < N_NODES);
    int cnt = 0, ocnt = 0;
    int   er[CAP];
    float ew[CAP], ec[CAP];
    if (active) {
        cnt  = min(ld_coh_i(&fill[v]), CAP);
        ocnt = ld_coh_i(ofl_cnt);          // expected 0
        #pragma unroll
        for (int k = 0; k < CAP; ++k) {
            bool in = (k < cnt);
            er[k] = 0; ew[k] = 0.0f; ec[k] = 0.0f;   // dummy -> S[0], broadcast
            if (in) {
                er[k] = csc_row[k * N_NODES + v];    // plain: written via st_coh,
                ew[k] = csc_w  [k * N_NODES + v];    // never cached stale (see r5)
                ec[k] = csc_c  [k * N_NODES + v];
            }
        }
    }

    // ---- 9 gather iterations: CAP independent coherent loads per node ----
    #pragma unroll 1
    for (int k = 1; k <= FLOW_ITERS - 1; ++k) {
        const float* Sp = (k & 1) ? S0 : S1;
        float*       Sn = (k & 1) ? S1 : S0;
        if (active) {
            float sk[CAP];
            #pragma unroll
            for (int t = 0; t < CAP; ++t) sk[t] = ld_coh(&Sp[er[t]]);
            float acc = 0.0f;
            #pragma unroll
            for (int t = 0; t < CAP; ++t) acc += ec[t] + ew[t] * sk[t];
            if (ocnt > 0) {                 // exactness fallback, ~never taken
                for (int o = 0; o < ocnt && o < OFL_MAX; ++o)
                    if (ld_coh_i(&ofl_v[o]) == v)
                        acc += ld_coh(&ofl_c[o]) +
                               ld_coh(&ofl_w[o]) * ld_coh(&Sp[ld_coh_i(&ofl_row[o])]);
            }
            st_coh(&Sn[v], acc);
        }
        gbar(barcnt, NBLK * (++bar));
    }

    // ---- flow_10[e] = w_e * (dpos_e + S_9[row_e])  (S_9 lives in S1) ----
    #pragma unroll
    for (int i = 0; i < EPT; ++i) {
        int e = tid + i * NTOT;
        if (e < N_EDGES) out[e] = wr[i] * (dposr[i] + ld_coh(&S1[rowr[i]]));
    }
}

extern "C" void kernel_launch(void* const* d_in, const int* in_sizes, int n_in,
                              void* d_out, int out_size, void* d_ws, size_t ws_size,
                              hipStream_t stream) {
    const float* demands  = (const float*)d_in[1];
    const int*   edge_row = (const int*)d_in[2];
    const int*   edge_col = (const int*)d_in[3];
    float*       out      = (float*)d_out;

    char* ws = (char*)d_ws;
    auto take = [&](size_t bytes) {
        void* p = (void*)ws;
        ws += (bytes + 127) & ~size_t(127);
        return p;
    };
    int*   deg     = (int*)  take(N_NODES * 4);
    int*   fill    = (int*)  take(N_NODES * 4);
    float* S0      = (float*)take(N_NODES * 4);
    float* S1      = (float*)take(N_NODES * 4);
    int*   csc_row = (int*)  take((size_t)CAP * N_NODES * 4);
    float* csc_w   = (float*)take((size_t)CAP * N_NODES * 4);
    float* csc_c   = (float*)take((size_t)CAP * N_NODES * 4);
    int*   ofl_cnt = (int*)  take(4);
    int*   ofl_v   = (int*)  take(OFL_MAX * 4);
    int*   ofl_row = (int*)  take(OFL_MAX * 4);
    float* ofl_w   = (float*)take(OFL_MAX * 4);
    float* ofl_c   = (float*)take(OFL_MAX * 4);
    int*   barcnt  = (int*)  take(4);

    mcf_fused<<<NBLK, NTHR, 0, stream>>>(demands, edge_row, edge_col, out,
                                         deg, fill, S0, S1,
                                         csc_row, csc_w, csc_c,
                                         ofl_cnt, ofl_v, ofl_row, ofl_w, ofl_c,
                                         barcnt);
}